// Round 5
// baseline (73.300 us; speedup 1.0000x reference)
//
#include <hip/hip_runtime.h>
#include <hip/hip_bf16.h>

// Causal flash-attention forward. B=4, L=2048, H=8, E=64, fp32 in/out.
// Layout: [B, L, H, E] -> ((b*L + l)*H + h)*E + e ; row stride H*E = 512 floats.
//
// prepass: K and V^T -> f16 swizzled LDS-image tiles in d_ws.
// main: 128-thread blocks (2 waves), each wave owns 32 q-rows as 2 fragment
// sets (ILP x2 in softmax chains; K/V fragments read once, used twice).
// Double-buffered global_load_lds staging (32 KB LDS -> 5 blocks/CU), swapped
// QK^T so P is lane-local and feeds mfma_f32_16x16x16f16 directly; row-sum l
// via ones-column MFMA; defer-max rescale skip (THR=8, exp2 domain).

#define Bc 4
#define Lc 2048
#define Hc 8
#define Ec 64
#define TB 64
#define NT (Lc / TB)                   // 32 tiles
#define BH_BYTES (NT * TB * Ec * 2)    // 262144
#define WS_V_OFF ((size_t)32 * BH_BYTES)

using f32x4 = __attribute__((ext_vector_type(4))) float;
using f16x8 = __attribute__((ext_vector_type(8))) _Float16;
using f16x4 = __attribute__((ext_vector_type(4))) _Float16;
using hf16x2 = __fp16 __attribute__((ext_vector_type(2)));   // cvt_pkrtz native type

static __device__ __forceinline__ unsigned int pk2(float lo, float hi) {
    union { hf16x2 h; unsigned int u; } c;
    c.h = __builtin_amdgcn_cvt_pkrtz(lo, hi);
    return c.u;
}

static __device__ __forceinline__ void gload16(const void* g, void* l) {
    __builtin_amdgcn_global_load_lds(
        (const __attribute__((address_space(1))) unsigned int*)g,
        (__attribute__((address_space(3))) unsigned int*)l, 16, 0, 0);
}

// ---------------- prepass: fp32 -> f16 swizzled tile images ----------------
__global__ __launch_bounds__(256)
void prep_kernel(const float* __restrict__ K, const float* __restrict__ V,
                 char* __restrict__ ws)
{
    __shared__ char vstage[64 * 144];   // [kv][72 f16], padded row

    const int bid = blockIdx.x;
    const int bh = bid >> 5, kt = bid & 31;
    const int b = bh >> 3, h = bh & 7;
    const int tid = threadIdx.x;
    const int r = tid >> 2, q4 = tid & 3;
    const int c0 = 16 * q4;
    const size_t base_bh = (size_t)b * Lc * Hc * Ec + (size_t)h * Ec;
    const int kbase = kt * TB;
    char* kimg = ws + (size_t)bh * BH_BYTES + (size_t)kt * 8192;
    char* vimg = ws + WS_V_OFF + (size_t)bh * BH_BYTES + (size_t)kt * 8192;

    const int rs = (r & 7) << 4;
    {   // K tile: row-major [kv][e], swizzled
        const float* kp = K + base_bh + (size_t)(kbase + r) * 512 + c0;
        unsigned int w[8];
        #pragma unroll
        for (int i = 0; i < 4; ++i) {
            float4 f = *(const float4*)(kp + 4 * i);
            w[2*i]   = pk2(f.x, f.y);
            w[2*i+1] = pk2(f.z, f.w);
        }
        *(uint4*)(kimg + r * 128 + ((32*q4)      ^ rs)) = *(uint4*)&w[0];
        *(uint4*)(kimg + r * 128 + ((32*q4 + 16) ^ rs)) = *(uint4*)&w[4];
    }
    {   // V tile -> LDS row-major (padded)
        const float* vp = V + base_bh + (size_t)(kbase + r) * 512 + c0;
        unsigned int w[8];
        #pragma unroll
        for (int i = 0; i < 4; ++i) {
            float4 f = *(const float4*)(vp + 4 * i);
            w[2*i]   = pk2(f.x, f.y);
            w[2*i+1] = pk2(f.z, f.w);
        }
        *(uint4*)(vstage + r * 144 + 32*q4)      = *(uint4*)&w[0];
        *(uint4*)(vstage + r * 144 + 32*q4 + 16) = *(uint4*)&w[4];
    }
    __syncthreads();
    {   // transpose: V^T rows e, cols kv, swizzled
        const int e = tid >> 2, kq = tid & 3, kv0 = 16 * kq;
        unsigned int w[8];
        #pragma unroll
        for (int i = 0; i < 8; ++i) {
            unsigned int lo = *(const unsigned short*)(vstage + (kv0 + 2*i)     * 144 + 2*e);
            unsigned int hi = *(const unsigned short*)(vstage + (kv0 + 2*i + 1) * 144 + 2*e);
            w[i] = lo | (hi << 16);
        }
        const int es = (e & 7) << 4;
        *(uint4*)(vimg + e * 128 + ((32*kq)      ^ es)) = *(uint4*)&w[0];
        *(uint4*)(vimg + e * 128 + ((32*kq + 16) ^ es)) = *(uint4*)&w[4];
    }
}

// ---------------- main kernel ----------------
__global__ __launch_bounds__(128, 3)
void fa_fwd_kernel(const float* __restrict__ Q, const char* __restrict__ ws,
                   float* __restrict__ Out)
{
    __shared__ char klds[2 * 8192];
    __shared__ char vlds[2 * 8192];

    const int bid = blockIdx.x;
    const int qi  = bid >> 5;
    const int bh  = bid & 31;
    const int b   = bh >> 3, h = bh & 7;
    const int qt  = (NT - 1) - qi;          // longest-running tiles first
    const int qbase = qt * TB;

    const int tid  = threadIdx.x;
    const int wid  = tid >> 6;              // 0..1
    const int lane = tid & 63;
    const int l15  = lane & 15;
    const int l4   = lane >> 4;

    const size_t base_bh = (size_t)b * Lc * Hc * Ec + (size_t)h * Ec;
    const char* kimg = ws + (size_t)bh * BH_BYTES;
    const char* vimg = ws + WS_V_OFF + (size_t)bh * BH_BYTES;
    const float SL2E = 0.125f * 1.44269504088896340736f;

    // loop-invariant swizzled LDS read offsets (row&7 == l15&7 throughout)
    const int sw  = (l15 & 7) << 4;
    const int ko0 = l15 * 128 + ((16 * l4)      ^ sw);
    const int ko1 = l15 * 128 + ((64 + 16 * l4) ^ sw);
    int vo[4];
    #pragma unroll
    for (int m = 0; m < 4; ++m) vo[m] = l15 * 128 + ((32 * m + 8 * l4) ^ sw);

    // constant ones B-fragment: B[k][0]=1 else 0 -> row-sum column
    f16x4 ones;
    {
        const _Float16 ov = (_Float16)((l15 == 0) ? 1.0f : 0.0f);
        ones[0] = ov; ones[1] = ov; ones[2] = ov; ones[3] = ov;
    }

    const int stoff = tid * 16;   // 0..2047; per-j base is wave-uniform

    // Q fragments for the wave's two q-sets, prescaled by scale*log2(e)
    f16x8 qa[2][2];
    #pragma unroll
    for (int g = 0; g < 2; ++g) {
        const int qrow = qbase + 32 * wid + 16 * g + l15;
        const float* qpr = Q + base_bh + (size_t)qrow * 512 + 8 * l4;
        float4 f0 = *(const float4*)(qpr);
        float4 f1 = *(const float4*)(qpr + 4);
        float4 f2 = *(const float4*)(qpr + 32);
        float4 f3 = *(const float4*)(qpr + 36);
        union { f16x8 v; unsigned int u[4]; } pk;
        pk.u[0] = pk2(f0.x * SL2E, f0.y * SL2E);
        pk.u[1] = pk2(f0.z * SL2E, f0.w * SL2E);
        pk.u[2] = pk2(f1.x * SL2E, f1.y * SL2E);
        pk.u[3] = pk2(f1.z * SL2E, f1.w * SL2E);
        qa[g][0] = pk.v;
        pk.u[0] = pk2(f2.x * SL2E, f2.y * SL2E);
        pk.u[1] = pk2(f2.z * SL2E, f2.w * SL2E);
        pk.u[2] = pk2(f3.x * SL2E, f3.y * SL2E);
        pk.u[3] = pk2(f3.z * SL2E, f3.w * SL2E);
        qa[g][1] = pk.v;
    }

    f32x4 o[2][4] = {};
    f32x4 ol[2] = {};
    float m_run[2] = {-1e30f, -1e30f};

    // stage tile 0
    #pragma unroll
    for (int j = 0; j < 4; ++j) {
        gload16(kimg + stoff + j * 2048, klds + stoff + j * 2048);
        gload16(vimg + stoff + j * 2048, vlds + stoff + j * 2048);
    }
    __syncthreads();

    for (int kt = 0; kt <= qt; ++kt) {
        const int cur = kt & 1;
        const char* kb = klds + cur * 8192;
        const char* vb = vlds + cur * 8192;

        if (kt < qt) {   // prefetch next tile into other buffer
            const char* ks = kimg + (size_t)(kt + 1) * 8192;
            const char* vs = vimg + (size_t)(kt + 1) * 8192;
            char* kd = klds + (cur ^ 1) * 8192;
            char* vd = vlds + (cur ^ 1) * 8192;
            #pragma unroll
            for (int j = 0; j < 4; ++j) {
                gload16(ks + stoff + j * 2048, kd + stoff + j * 2048);
                gload16(vs + stoff + j * 2048, vd + stoff + j * 2048);
            }
        }

        // S^T = K·Q^T : lane holds S[kv=16n+4*l4+r][q = qrow0g + l15]
        // K fragments read once, used for both q-sets.
        f32x4 s[2][4];
        #pragma unroll
        for (int n = 0; n < 4; ++n) {
            f16x8 a0 = *(const f16x8*)(kb + n * 2048 + ko0);
            f16x8 a1 = *(const f16x8*)(kb + n * 2048 + ko1);
            #pragma unroll
            for (int g = 0; g < 2; ++g) {
                f32x4 z = {0.f, 0.f, 0.f, 0.f};
                z = __builtin_amdgcn_mfma_f32_16x16x32_f16(a0, qa[g][0], z, 0, 0, 0);
                z = __builtin_amdgcn_mfma_f32_16x16x32_f16(a1, qa[g][1], z, 0, 0, 0);
                s[g][n] = z;
            }
        }

        if (kt == qt) {   // causal mask on the diagonal tile
            #pragma unroll
            for (int g = 0; g < 2; ++g) {
                const int q_g = qbase + 32 * wid + 16 * g + l15;
                #pragma unroll
                for (int n = 0; n < 4; ++n) {
                    #pragma unroll
                    for (int r = 0; r < 4; ++r) {
                        const int kv_g = kt * TB + 16 * n + 4 * l4 + r;
                        if (kv_g > q_g) s[g][n][r] = -1e30f;
                    }
                }
            }
        }

        // col max per q-set (two chains interleave for ILP)
        float pmax[2];
        #pragma unroll
        for (int g = 0; g < 2; ++g) {
            float a0 = fmaxf(s[g][0][0], s[g][0][1]), a1 = fmaxf(s[g][0][2], s[g][0][3]);
            float a2 = fmaxf(s[g][1][0], s[g][1][1]), a3 = fmaxf(s[g][1][2], s[g][1][3]);
            float a4 = fmaxf(s[g][2][0], s[g][2][1]), a5 = fmaxf(s[g][2][2], s[g][2][3]);
            float a6 = fmaxf(s[g][3][0], s[g][3][1]), a7 = fmaxf(s[g][3][2], s[g][3][3]);
            float pm = fmaxf(fmaxf(fmaxf(a0, a1), fmaxf(a2, a3)),
                             fmaxf(fmaxf(a4, a5), fmaxf(a6, a7)));
            pm = fmaxf(pm, __shfl_xor(pm, 16, 64));
            pm = fmaxf(pm, __shfl_xor(pm, 32, 64));
            pmax[g] = pm;
        }

        // defer-max: rescale only when the max grew past THR=8 (exp2 domain)
        #pragma unroll
        for (int g = 0; g < 2; ++g) {
            if (!__all(pmax[g] - m_run[g] <= 8.0f)) {
                const float m_new = fmaxf(m_run[g], pmax[g]);
                const float fac = __builtin_exp2f(m_run[g] - m_new);
                m_run[g] = m_new;
                float fr[4];
                #pragma unroll
                for (int r = 0; r < 4; ++r) fr[r] = __shfl(fac, 4 * l4 + r, 64);
                #pragma unroll
                for (int c = 0; c < 4; ++c)
                    #pragma unroll
                    for (int r = 0; r < 4; ++r) o[g][c][r] *= fr[r];
                #pragma unroll
                for (int r = 0; r < 4; ++r) ol[g][r] *= fr[r];
            }
        }

        // P = exp2(s - m_run), packed f16
        unsigned int ph[2][4][2];
        #pragma unroll
        for (int g = 0; g < 2; ++g) {
            #pragma unroll
            for (int n = 0; n < 4; ++n) {
                float p0 = __builtin_exp2f(s[g][n][0] - m_run[g]);
                float p1 = __builtin_exp2f(s[g][n][1] - m_run[g]);
                float p2 = __builtin_exp2f(s[g][n][2] - m_run[g]);
                float p3 = __builtin_exp2f(s[g][n][3] - m_run[g]);
                ph[g][n][0] = pk2(p0, p1);
                ph[g][n][1] = pk2(p2, p3);
            }
        }

        // O += P·V and l += P·1 ; V fragments read once, used for both q-sets
        #pragma unroll
        for (int m = 0; m < 4; ++m) {
            f16x4 vbf[4];
            #pragma unroll
            for (int c = 0; c < 4; ++c)
                vbf[c] = *(const f16x4*)(vb + c * 2048 + vo[m]);
            #pragma unroll
            for (int g = 0; g < 2; ++g) {
                union { f16x4 h; unsigned int u[2]; } pa;
                pa.u[0] = ph[g][m][0]; pa.u[1] = ph[g][m][1];
                ol[g] = __builtin_amdgcn_mfma_f32_16x16x16f16(pa.h, ones, ol[g], 0, 0, 0);
                #pragma unroll
                for (int c = 0; c < 4; ++c)
                    o[g][c] = __builtin_amdgcn_mfma_f32_16x16x16f16(pa.h, vbf[c], o[g][c], 0, 0, 0);
            }
        }
        __syncthreads();   // drains vmcnt/lgkmcnt: prefetch landed, reads done
    }

    // epilogue: normalize by l (col 0 of ol, lanes l15==0) and store
    float* op = Out + base_bh;
    #pragma unroll
    for (int g = 0; g < 2; ++g) {
        float ir[4];
        #pragma unroll
        for (int r = 0; r < 4; ++r) {
            const float iv = 1.0f / ol[g][r];
            ir[r] = __shfl(iv, 16 * l4, 64);   // broadcast from l15==0 lane
        }
        const int qrow0 = qbase + 32 * wid + 16 * g;
        #pragma unroll
        for (int c = 0; c < 4; ++c)
            #pragma unroll
            for (int r = 0; r < 4; ++r)
                op[(size_t)(qrow0 + 4 * l4 + r) * 512 + 16 * c + l15] = o[g][c][r] * ir[r];
    }
}

extern "C" void kernel_launch(void* const* d_in, const int* in_sizes, int n_in,
                              void* d_out, int out_size, void* d_ws, size_t ws_size,
                              hipStream_t stream) {
    const float* Q = (const float*)d_in[0];
    const float* K = (const float*)d_in[1];
    const float* V = (const float*)d_in[2];
    float* O = (float*)d_out;
    char* ws = (char*)d_ws;   // 16 MB tile images
    hipLaunchKernelGGL(prep_kernel, dim3(Bc * Hc * NT), dim3(256), 0, stream, K, V, ws);
    hipLaunchKernelGGL(fa_fwd_kernel, dim3(NT * Bc * Hc), dim3(128), 0, stream, Q, ws, O);
}

// Round 6
// 60.922 us; speedup vs baseline: 1.2032x; 1.2032x over previous
//
#include <hip/hip_runtime.h>

// Causal flash-attention forward. B=4, L=2048, H=8, E=64, fp32 in/out.
// Layout: [B, L, H, E] -> ((b*L + l)*H + h)*E + e ; row stride H*E = 512 floats.
//
// prepass: K and V^T -> f16 tiles in d_ws, stored in FRAGMENT-CONSUMPTION order
//   (frag j of a 64x64 tile at tile_base + j*1024 + lane*16) so the main kernel
//   loads MFMA operands with perfectly-coalesced global_load_dwordx4.
// main: one WAVE per 32 q-rows, fully independent: no LDS, no barriers.
//   K/V tiles stream L2->regs (register prefetch one tile ahead); swapped QK^T
//   keeps P lane-local feeding mfma_f32_16x16x16f16; row-sum l via ones-column
//   MFMA; defer-max rescale skip (THR=8, exp2 domain). Longest jobs first,
//   bid&7 XCD slotting keeps each XCD's L2 on its own 4 bh (2 MB working set).

#define Bc 4
#define Lc 2048
#define Hc 8
#define Ec 64
#define KVT 64
#define NKV (Lc / KVT)                 // 32 kv tiles
#define TILEB 8192
#define BHB ((size_t)NKV * TILEB)      // 256 KB per bh
#define WSV ((size_t)32 * BHB)         // V images at +8 MB

using f32x4 = __attribute__((ext_vector_type(4))) float;
using f16x8 = __attribute__((ext_vector_type(8))) _Float16;
using f16x4 = __attribute__((ext_vector_type(4))) _Float16;
using hf16x2 = __fp16 __attribute__((ext_vector_type(2)));

static __device__ __forceinline__ unsigned int pk2(float lo, float hi) {
    union { hf16x2 h; unsigned int u; } c;
    c.h = __builtin_amdgcn_cvt_pkrtz(lo, hi);
    return c.u;
}

// ---------------- prepass: fp32 -> f16 fragment-ordered tile images ----------
__global__ __launch_bounds__(256)
void prep_kernel(const float* __restrict__ K, const float* __restrict__ V,
                 char* __restrict__ ws)
{
    __shared__ char kst[64 * 128];   // K tile rows  [kv][e] f16
    __shared__ char vst[64 * 144];   // V tile rows, padded (transpose staging)
    __shared__ char vtt[64 * 128];   // V^T [e][kv] f16

    const int bid = blockIdx.x;
    const int bh = bid >> 5, kt = bid & 31;
    const int b = bh >> 3, h = bh & 7;
    const int tid = threadIdx.x;
    const size_t base = (size_t)b * Lc * Hc * Ec + (size_t)h * Ec;

    {   // phase A: load + convert rows
        const int r = tid >> 2, q4 = tid & 3, c0 = 16 * q4;
        const float* kp = K + base + (size_t)(kt * 64 + r) * 512 + c0;
        const float* vp = V + base + (size_t)(kt * 64 + r) * 512 + c0;
        unsigned int wk[8], wv[8];
        #pragma unroll
        for (int i = 0; i < 4; ++i) {
            float4 fk = *(const float4*)(kp + 4 * i);
            float4 fv = *(const float4*)(vp + 4 * i);
            wk[2*i]   = pk2(fk.x, fk.y); wk[2*i+1] = pk2(fk.z, fk.w);
            wv[2*i]   = pk2(fv.x, fv.y); wv[2*i+1] = pk2(fv.z, fv.w);
        }
        *(uint4*)(kst + r * 128 + 2 * c0)      = *(uint4*)&wk[0];
        *(uint4*)(kst + r * 128 + 2 * c0 + 16) = *(uint4*)&wk[4];
        *(uint4*)(vst + r * 144 + 2 * c0)      = *(uint4*)&wv[0];
        *(uint4*)(vst + r * 144 + 2 * c0 + 16) = *(uint4*)&wv[4];
    }
    __syncthreads();
    {   // phase B: transpose V -> V^T
        const int e = tid >> 2, kq = tid & 3, kv0 = 16 * kq;
        unsigned int w[8];
        #pragma unroll
        for (int i = 0; i < 8; ++i) {
            unsigned int lo = *(const unsigned short*)(vst + (kv0 + 2*i)     * 144 + 2*e);
            unsigned int hi = *(const unsigned short*)(vst + (kv0 + 2*i + 1) * 144 + 2*e);
            w[i] = lo | (hi << 16);
        }
        *(uint4*)(vtt + e * 128 + 2 * kv0)      = *(uint4*)&w[0];
        *(uint4*)(vtt + e * 128 + 2 * kv0 + 16) = *(uint4*)&w[4];
    }
    __syncthreads();
    {   // phase C: emit fragment-ordered images
        const int lane = tid & 63, qq = tid >> 6;   // wave qq handles frag group qq
        const int l15 = lane & 15, l4 = lane >> 4;
        char* ko = ws + (size_t)bh * BHB + (size_t)kt * TILEB;
        char* vo = ws + WSV + (size_t)bh * BHB + (size_t)kt * TILEB;
        // K frags f=2qq (h=0), 2qq+1 (h=1): K[16qq+l15][32h + 8l4 + j]
        uint4 k0 = *(const uint4*)(kst + (16 * qq + l15) * 128 + 16 * l4);
        uint4 k1 = *(const uint4*)(kst + (16 * qq + l15) * 128 + 64 + 16 * l4);
        *(uint4*)(ko + (2 * qq)     * 1024 + lane * 16) = k0;
        *(uint4*)(ko + (2 * qq + 1) * 1024 + lane * 16) = k1;
        // V frags f=4qq+c: V^T[16c+l15][16qq + 4l4 + j]; pack (c,c+1) per uint4
        unsigned long long vv[4];
        #pragma unroll
        for (int c = 0; c < 4; ++c)
            vv[c] = *(const unsigned long long*)(vtt + (16 * c + l15) * 128 + 32 * qq + 8 * l4);
        uint4 v01, v23;
        v01.x = (unsigned)vv[0]; v01.y = (unsigned)(vv[0] >> 32);
        v01.z = (unsigned)vv[1]; v01.w = (unsigned)(vv[1] >> 32);
        v23.x = (unsigned)vv[2]; v23.y = (unsigned)(vv[2] >> 32);
        v23.z = (unsigned)vv[3]; v23.w = (unsigned)(vv[3] >> 32);
        *(uint4*)(vo + (2 * qq)     * 1024 + lane * 16) = v01;
        *(uint4*)(vo + (2 * qq + 1) * 1024 + lane * 16) = v23;
    }
}

// ---------------- main kernel: one independent wave per 32 q-rows ------------
__global__ __launch_bounds__(64, 2)
void fa_fwd_kernel(const float* __restrict__ Q, const char* __restrict__ ws,
                   float* __restrict__ Out)
{
    const int bid = blockIdx.x;
    const int xcd = bid & 7;                  // round-robin XCD slot (heuristic)
    const int rr  = bid >> 3;                 // 0..255
    const int bh  = 4 * xcd + (rr & 3);       // each XCD works 4 bh (2 MB in L2)
    const int qi  = rr >> 2;                  // 0..63
    const int qt  = 63 - qi;                  // longest jobs dispatched first
    const int steps = (qt >> 1) + 1;          // kv tiles needed (causal)
    const int b = bh >> 3, h = bh & 7;

    const int lane = threadIdx.x;
    const int l15 = lane & 15, l4 = lane >> 4;
    const size_t base = (size_t)b * Lc * Hc * Ec + (size_t)h * Ec;
    const char* kimg = ws + (size_t)bh * BHB + lane * 16;
    const char* vimg = ws + WSV + (size_t)bh * BHB + lane * 16;
    const float SL2E = 0.125f * 1.44269504088896340736f;

    // ones B-fragment: col 0 only -> row-sum of P via MFMA
    f16x4 ones;
    {
        const _Float16 ov = (_Float16)((l15 == 0) ? 1.0f : 0.0f);
        ones[0] = ov; ones[1] = ov; ones[2] = ov; ones[3] = ov;
    }

    // Q fragments (B-operand), 2 q-sets of 16 rows, prescaled by scale*log2(e)
    f16x8 qa[2][2];
    #pragma unroll
    for (int g = 0; g < 2; ++g) {
        const int qrow = qt * 32 + 16 * g + l15;
        const float* qpr = Q + base + (size_t)qrow * 512 + 8 * l4;
        float4 f0 = *(const float4*)(qpr);
        float4 f1 = *(const float4*)(qpr + 4);
        float4 f2 = *(const float4*)(qpr + 32);
        float4 f3 = *(const float4*)(qpr + 36);
        union { f16x8 v; unsigned int u[4]; } pk;
        pk.u[0] = pk2(f0.x * SL2E, f0.y * SL2E);
        pk.u[1] = pk2(f0.z * SL2E, f0.w * SL2E);
        pk.u[2] = pk2(f1.x * SL2E, f1.y * SL2E);
        pk.u[3] = pk2(f1.z * SL2E, f1.w * SL2E);
        qa[g][0] = pk.v;
        pk.u[0] = pk2(f2.x * SL2E, f2.y * SL2E);
        pk.u[1] = pk2(f2.z * SL2E, f2.w * SL2E);
        pk.u[2] = pk2(f3.x * SL2E, f3.y * SL2E);
        pk.u[3] = pk2(f3.z * SL2E, f3.w * SL2E);
        qa[g][1] = pk.v;
    }

    f32x4 o[2][4] = {};
    f32x4 ol[2] = {};
    float m_run[2] = {-1e30f, -1e30f};

    // prologue: load tile 0 operand fragments into registers
    uint4 kf[8], vf[8];
    #pragma unroll
    for (int j = 0; j < 8; ++j) kf[j] = *(const uint4*)(kimg + j * 1024);
    #pragma unroll
    for (int j = 0; j < 8; ++j) vf[j] = *(const uint4*)(vimg + j * 1024);

    #pragma unroll 1
    for (int kt = 0; kt < steps; ++kt) {
        // S^T = K·Q^T : lane holds S[kv = 64kt+16n+4l4+r][q = 32qt+16g+l15]
        f32x4 s[2][4];
        #pragma unroll
        for (int n = 0; n < 4; ++n) {
            union { uint4 u; f16x8 h; } a0, a1;
            a0.u = kf[2 * n]; a1.u = kf[2 * n + 1];
            #pragma unroll
            for (int g = 0; g < 2; ++g) {
                f32x4 z = {0.f, 0.f, 0.f, 0.f};
                z = __builtin_amdgcn_mfma_f32_16x16x32_f16(a0.h, qa[g][0], z, 0, 0, 0);
                z = __builtin_amdgcn_mfma_f32_16x16x32_f16(a1.h, qa[g][1], z, 0, 0, 0);
                s[g][n] = z;
            }
        }

        // register-prefetch next K tile (K regs dead after QK issue)
        if (kt + 1 < steps) {
            const char* kp = kimg + (size_t)(kt + 1) * TILEB;
            #pragma unroll
            for (int j = 0; j < 8; ++j) kf[j] = *(const uint4*)(kp + j * 1024);
        }

        if (kt == steps - 1) {   // causal mask (always on last tile)
            #pragma unroll
            for (int g = 0; g < 2; ++g) {
                const int q_g = qt * 32 + 16 * g + l15;
                #pragma unroll
                for (int n = 0; n < 4; ++n) {
                    #pragma unroll
                    for (int r2 = 0; r2 < 4; ++r2) {
                        const int kv_g = kt * 64 + 16 * n + 4 * l4 + r2;
                        if (kv_g > q_g) s[g][n][r2] = -1e30f;
                    }
                }
            }
        }

        // online softmax (scalar per q-col; two independent chains for ILP)
        float pmax[2];
        #pragma unroll
        for (int g = 0; g < 2; ++g) {
            float a0 = fmaxf(s[g][0][0], s[g][0][1]), a1 = fmaxf(s[g][0][2], s[g][0][3]);
            float a2 = fmaxf(s[g][1][0], s[g][1][1]), a3 = fmaxf(s[g][1][2], s[g][1][3]);
            float a4 = fmaxf(s[g][2][0], s[g][2][1]), a5 = fmaxf(s[g][2][2], s[g][2][3]);
            float a6 = fmaxf(s[g][3][0], s[g][3][1]), a7 = fmaxf(s[g][3][2], s[g][3][3]);
            float pm = fmaxf(fmaxf(fmaxf(a0, a1), fmaxf(a2, a3)),
                             fmaxf(fmaxf(a4, a5), fmaxf(a6, a7)));
            pm = fmaxf(pm, __shfl_xor(pm, 16, 64));
            pm = fmaxf(pm, __shfl_xor(pm, 32, 64));
            pmax[g] = pm;
        }
        #pragma unroll
        for (int g = 0; g < 2; ++g) {
            if (!__all(pmax[g] - m_run[g] <= 8.0f)) {   // defer-max (THR=8)
                const float m_new = fmaxf(m_run[g], pmax[g]);
                const float fac = __builtin_exp2f(m_run[g] - m_new);
                m_run[g] = m_new;
                float fr[4];
                #pragma unroll
                for (int r2 = 0; r2 < 4; ++r2) fr[r2] = __shfl(fac, 4 * l4 + r2, 64);
                #pragma unroll
                for (int c = 0; c < 4; ++c)
                    #pragma unroll
                    for (int r2 = 0; r2 < 4; ++r2) o[g][c][r2] *= fr[r2];
                #pragma unroll
                for (int r2 = 0; r2 < 4; ++r2) ol[g][r2] *= fr[r2];
            }
        }

        // P = exp2(s - m), packed f16 (A-frag layout: k = 4*l4 + j)
        unsigned int ph[2][4][2];
        #pragma unroll
        for (int g = 0; g < 2; ++g) {
            #pragma unroll
            for (int n = 0; n < 4; ++n) {
                float p0 = __builtin_exp2f(s[g][n][0] - m_run[g]);
                float p1 = __builtin_exp2f(s[g][n][1] - m_run[g]);
                float p2 = __builtin_exp2f(s[g][n][2] - m_run[g]);
                float p3 = __builtin_exp2f(s[g][n][3] - m_run[g]);
                ph[g][n][0] = pk2(p0, p1);
                ph[g][n][1] = pk2(p2, p3);
            }
        }

        // O += P·V ; l += P·1
        #pragma unroll
        for (int m = 0; m < 4; ++m) {
            union { uint4 u; f16x4 h[2]; } w0, w1;
            w0.u = vf[2 * m]; w1.u = vf[2 * m + 1];
            #pragma unroll
            for (int g = 0; g < 2; ++g) {
                union { f16x4 h; unsigned int u[2]; } pa;
                pa.u[0] = ph[g][m][0]; pa.u[1] = ph[g][m][1];
                ol[g] = __builtin_amdgcn_mfma_f32_16x16x16f16(pa.h, ones, ol[g], 0, 0, 0);
                o[g][0] = __builtin_amdgcn_mfma_f32_16x16x16f16(pa.h, w0.h[0], o[g][0], 0, 0, 0);
                o[g][1] = __builtin_amdgcn_mfma_f32_16x16x16f16(pa.h, w0.h[1], o[g][1], 0, 0, 0);
                o[g][2] = __builtin_amdgcn_mfma_f32_16x16x16f16(pa.h, w1.h[0], o[g][2], 0, 0, 0);
                o[g][3] = __builtin_amdgcn_mfma_f32_16x16x16f16(pa.h, w1.h[1], o[g][3], 0, 0, 0);
            }
        }

        // register-prefetch next V tile (V regs dead after PV issue)
        if (kt + 1 < steps) {
            const char* vp2 = vimg + (size_t)(kt + 1) * TILEB;
            #pragma unroll
            for (int j = 0; j < 8; ++j) vf[j] = *(const uint4*)(vp2 + j * 1024);
        }
    }

    // epilogue: normalize by l (col 0 of ol, lanes l15==0) and store fp32
    float* op = Out + base;
    #pragma unroll
    for (int g = 0; g < 2; ++g) {
        float ir[4];
        #pragma unroll
        for (int r2 = 0; r2 < 4; ++r2) {
            const float iv = 1.0f / ol[g][r2];
            ir[r2] = __shfl(iv, 16 * l4, 64);   // from the l15==0 lane of this row group
        }
        const int qrow0 = qt * 32 + 16 * g;
        #pragma unroll
        for (int c = 0; c < 4; ++c)
            #pragma unroll
            for (int r2 = 0; r2 < 4; ++r2)
                op[(size_t)(qrow0 + 4 * l4 + r2) * 512 + 16 * c + l15] = o[g][c][r2] * ir[r2];
    }
}

extern "C" void kernel_launch(void* const* d_in, const int* in_sizes, int n_in,
                              void* d_out, int out_size, void* d_ws, size_t ws_size,
                              hipStream_t stream) {
    const float* Q = (const float*)d_in[0];
    const float* K = (const float*)d_in[1];
    const float* V = (const float*)d_in[2];
    float* O = (float*)d_out;
    char* ws = (char*)d_ws;   // 16 MB fragment-ordered tile images
    hipLaunchKernelGGL(prep_kernel, dim3(32 * NKV), dim3(256), 0, stream, K, V, ws);
    hipLaunchKernelGGL(fa_fwd_kernel, dim3(2048), dim3(64), 0, stream, Q, ws, O);
}